// Round 5
// baseline (20262.808 us; speedup 1.0000x reference)
//
#include <hip/hip_runtime.h>
#include <hip/hip_bf16.h>

#define BATCH 4096
#define DIM   512
#define HID   2048
#define NSTEPS 20
#define GRID_NB 512

typedef __attribute__((ext_vector_type(8))) short short8;
typedef __attribute__((ext_vector_type(4))) short short4v;
typedef __attribute__((ext_vector_type(4))) float floatx4;

#define GLL(dst, src) __builtin_amdgcn_global_load_lds( \
    (const __attribute__((address_space(1))) void*)(src), \
    (__attribute__((address_space(3))) void*)(dst), 16, 0, 0)

__device__ __forceinline__ short f2bf(float x) {
    union { float f; unsigned u; } v; v.f = x;
    unsigned r = v.u + 0x7fffu + ((v.u >> 16) & 1u);
    return (short)(r >> 16);
}

// tanh(x) = 1 - 2*rcp(1 + exp2(2*log2e*x)); saturates correctly at +-inf
__device__ __forceinline__ float fast_tanh(float x) {
    float e = __builtin_amdgcn_exp2f(x * 2.8853900817779268f);
    float r = __builtin_amdgcn_rcpf(1.0f + e);
    return 1.0f - 2.0f * r;
}

// dst[n][k] = bf16(src[k][n]); src is K x N row-major fp32
__global__ void transpose_cvt(const float* __restrict__ src, short* __restrict__ dst,
                              int K, int N) {
    __shared__ float tile[32][33];
    int k0 = blockIdx.x * 32, n0 = blockIdx.y * 32;
    int tx = threadIdx.x, ty = threadIdx.y;
    #pragma unroll
    for (int r = ty; r < 32; r += 8)
        tile[r][tx] = src[(size_t)(k0 + r) * N + n0 + tx];
    __syncthreads();
    #pragma unroll
    for (int r = ty; r < 32; r += 8)
        dst[(size_t)(n0 + r) * K + k0 + tx] = f2bf(tile[tx][r]);
}

__global__ void extract_row(const float* __restrict__ W1, float* __restrict__ w1last) {
    int i = blockIdx.x * 256 + threadIdx.x;
    w1last[i] = W1[(size_t)DIM * HID + i];
}

__global__ void init_abuf(const float* __restrict__ z0, short* __restrict__ abuf) {
    size_t i = (size_t)(blockIdx.x * 256 + threadIdx.x) * 4;
    float4 zv = *(const float4*)(z0 + i);
    short4v o;
    o[0] = f2bf(zv.x); o[1] = f2bf(zv.y); o[2] = f2bf(zv.z); o[3] = f2bf(zv.w);
    *(short4v*)(abuf + i) = o;
}

// Monotonic-ticket grid barrier. All 512 blocks are co-resident (64 KB LDS ->
// 2 blocks/CU, launch_bounds caps VGPR<=256 -> 8 waves/CU), so spin is safe.
// AGENT-scope atomics + __threadfence give cross-XCD release/acquire (per-XCD
// L2s are non-coherent; plain loads would see stale data).
__device__ __forceinline__ void grid_sync(unsigned* bar) {
    __syncthreads();                       // per-wave vmcnt(0) drain: block's stores done
    if (threadIdx.x == 0) {
        __threadfence();                   // release: writeback to coherent point
        unsigned old = __hip_atomic_fetch_add(bar, 1u, __ATOMIC_ACQ_REL,
                                              __HIP_MEMORY_SCOPE_AGENT);
        unsigned goal = (old / GRID_NB + 1u) * GRID_NB;
        while (__hip_atomic_load(bar, __ATOMIC_RELAXED,
                                 __HIP_MEMORY_SCOPE_AGENT) < goal)
            __builtin_amdgcn_s_sleep(2);
        __threadfence();                   // acquire: invalidate stale cache lines
    }
    __syncthreads();
}

// Whole RK4 loop in ONE launch: 20 steps x 4 evals x (gemm1 + gemm2), with a
// software grid barrier between phases. Removes 159 kernel launches + drains.
// Phase 1 (gemm1): ROUND-0 VERBATIM -- 128x128 tile, BK=128, 4 waves,
//   XOR-swizzled LDS, 2 blocks/CU cross-block overlap preserved.
// Phase 2 (gemm2): round-0 structure at 256 thr -- 4-wave K-split (K=512/wave,
//   8 x BK=64), per-wave private 16 KB slab, no barriers in K-loop; reduce
//   sums 4 partials. kacc/z are same-block RMW across evals (no sync needed);
//   hidden/abuf cross blocks and are barrier-protected.
__global__ __launch_bounds__(256, 2)
void rk4_persistent(const short* __restrict__ W1t, const short* __restrict__ W2t,
                    const float* __restrict__ b1, const float* __restrict__ b2,
                    const float* __restrict__ w1last,
                    float* __restrict__ z, float* __restrict__ kacc,
                    short* __restrict__ abuf, short* __restrict__ hidden,
                    const float* __restrict__ t0p, const float* __restrict__ t1p,
                    unsigned* __restrict__ bar) {
    __shared__ short lds[32768];    // 64 KB, aliased: g1 {A 32K | B 32K}, g2 {4 x 16K slabs}
    const int tid = threadIdx.x;
    const int lane = tid & 63;
    const int wave = tid >> 6;      // 0..3
    const int vb = blockIdx.x;      // 0..511

    const int fr = lane & 15;
    const int fkc = lane >> 4;      // 0..3
    const int rx = fr & 7;

    // gemm1 tile mapping (as round-0 grid(32,16), x fastest over M)
    const int bm1 = (vb & 31) * 128;
    const int bn1 = (vb >> 5) * 128;
    const int wm = wave >> 1, wn = wave & 1;
    // gemm2 tile mapping (as round-0 grid(64,8), x fastest over M)
    const int bm2 = (vb & 63) * 64;
    const int bn2 = (vb >> 6) * 64;
    const int kbase = wave * 512;   // 4-way K-split over HID
    const int l3 = lane >> 3;       // 0..7
    const int gch = (lane & 7) ^ l3;

    short* Alds = lds;              // gemm1 A tile 128x128
    short* Blds = lds + 16384;      // gemm1 B tile 128x128
    short* slabA = &lds[wave * 8192];   // gemm2 per-wave A 64x64
    short* slabB = slabA + 4096;        // gemm2 per-wave B 64x64

    const float t0 = t0p[0], t1 = t1p[0];
    const float h = (t1 - t0) / (float)NSTEPS;
    const float h6 = h / 6.0f;

    #pragma unroll 1
    for (int se = 0; se < NSTEPS * 4; ++se) {
        const int ev = se & 3;
        const float fi = (float)(se >> 2);
        const float c_t = (ev == 0) ? 0.0f : ((ev == 3) ? 1.0f : 0.5f);
        const float teval = t0 + (fi + c_t) * h;

        // ================= phase 1: hidden = tanh(abuf @ W1t^T + b1 + teval*w1last)
        {
            floatx4 acc[4][4];
            #pragma unroll
            for (int i = 0; i < 4; i++)
                #pragma unroll
                for (int j = 0; j < 4; j++) acc[i][j] = (floatx4)0.f;

            for (int kk = 0; kk < DIM; kk += 128) {
                #pragma unroll
                for (int p = 0; p < 8; p++) {
                    int c = tid + p * 256;
                    int row = c >> 4;
                    int ci = c & 15;
                    int g = ((ci & 7) ^ (row & 7)) | (ci & 8);
                    GLL(&Alds[c * 8], abuf + (size_t)(bm1 + row) * DIM + kk + g * 8);
                    GLL(&Blds[c * 8], W1t  + (size_t)(bn1 + row) * DIM + kk + g * 8);
                }
                __syncthreads();               // forced vmcnt(0): staging landed
                #pragma unroll
                for (int s = 0; s < 4; s++) {
                    const int lc = s * 4 + fkc;
                    const int slot = ((((lc & 7) ^ rx) | (lc & 8))) * 8;
                    short8 af[4], bfr[4];
                    #pragma unroll
                    for (int mt = 0; mt < 4; mt++)
                        af[mt] = *(const short8*)&Alds[(wm * 64 + mt * 16 + fr) * 128 + slot];
                    #pragma unroll
                    for (int nt = 0; nt < 4; nt++)
                        bfr[nt] = *(const short8*)&Blds[(wn * 64 + nt * 16 + fr) * 128 + slot];
                    #pragma unroll
                    for (int mt = 0; mt < 4; mt++)
                        #pragma unroll
                        for (int nt = 0; nt < 4; nt++)
                            acc[mt][nt] = __builtin_amdgcn_mfma_f32_16x16x32_bf16(bfr[nt], af[mt], acc[mt][nt], 0, 0, 0);
                }
                __syncthreads();
            }
            #pragma unroll
            for (int mt = 0; mt < 4; mt++) {
                int m = bm1 + wm * 64 + mt * 16 + fr;
                short* hrow = hidden + (size_t)m * HID;
                #pragma unroll
                for (int nt = 0; nt < 4; nt++) {
                    int n0 = bn1 + wn * 64 + nt * 16 + fkc * 4;
                    float4 bb = *(const float4*)&b1[n0];
                    float4 wl = *(const float4*)&w1last[n0];
                    short4v o;
                    o[0] = f2bf(fast_tanh(acc[mt][nt][0] + bb.x + teval * wl.x));
                    o[1] = f2bf(fast_tanh(acc[mt][nt][1] + bb.y + teval * wl.y));
                    o[2] = f2bf(fast_tanh(acc[mt][nt][2] + bb.z + teval * wl.z));
                    o[3] = f2bf(fast_tanh(acc[mt][nt][3] + bb.w + teval * wl.w));
                    *(short4v*)&hrow[n0] = o;
                }
            }
        }
        grid_sync(bar);     // hidden visible device-wide

        // ================= phase 2: k = hidden @ W2t^T + b2 (+ fused RK update)
        {
            const int mode = (ev == 0) ? 0 : ((ev == 3) ? 2 : 1);
            const float wk = (mode == 1) ? 2.0f : 1.0f;
            const float alpha = (ev == 0 || ev == 1) ? 0.5f : ((ev == 2) ? 1.0f : 0.0f);
            const float ah = alpha * h;

            floatx4 acc[4][4];
            #pragma unroll
            for (int i = 0; i < 4; i++)
                #pragma unroll
                for (int j = 0; j < 4; j++) acc[i][j] = (floatx4)0.f;

            #pragma unroll
            for (int it = 0; it < 8; ++it) {
                const int k0 = kbase + it * 64;
                __builtin_amdgcn_s_waitcnt(0xC07F);   // lgkmcnt(0): own reads done
                #pragma unroll
                for (int j = 0; j < 8; j++) {
                    int row = j * 8 + l3;
                    GLL(&slabA[j * 512 + lane * 8], hidden + (size_t)(bm2 + row) * HID + k0 + gch * 8);
                    GLL(&slabB[j * 512 + lane * 8], W2t    + (size_t)(bn2 + row) * HID + k0 + gch * 8);
                }
                __builtin_amdgcn_sched_barrier(0);
                __builtin_amdgcn_s_waitcnt(0x0F70);   // vmcnt(0), per-wave
                __builtin_amdgcn_sched_barrier(0);
                #pragma unroll
                for (int s = 0; s < 2; s++) {
                    const int slot = ((s * 4 + fkc) ^ rx) * 8;
                    short8 af[4], bfr[4];
                    #pragma unroll
                    for (int mt = 0; mt < 4; mt++)
                        af[mt] = *(const short8*)&slabA[(mt * 16 + fr) * 64 + slot];
                    #pragma unroll
                    for (int nt = 0; nt < 4; nt++)
                        bfr[nt] = *(const short8*)&slabB[(nt * 16 + fr) * 64 + slot];
                    #pragma unroll
                    for (int mt = 0; mt < 4; mt++)
                        #pragma unroll
                        for (int nt = 0; nt < 4; nt++)
                            acc[mt][nt] = __builtin_amdgcn_mfma_f32_16x16x32_bf16(af[mt], bfr[nt], acc[mt][nt], 0, 0, 0);
                }
                __builtin_amdgcn_sched_barrier(0);
            }

            // write partial acc (fp32 64x64) to own slab; reduce 4 waves
            __builtin_amdgcn_s_waitcnt(0xC07F);
            float* fslab = (float*)slabA;
            #pragma unroll
            for (int mt = 0; mt < 4; mt++)
                #pragma unroll
                for (int nt = 0; nt < 4; nt++)
                    #pragma unroll
                    for (int r = 0; r < 4; r++) {
                        int row = mt * 16 + fkc * 4 + r;
                        int col = nt * 16 + fr;
                        fslab[row * 64 + col] = acc[mt][nt][r];
                    }
            __syncthreads();

            // 256 threads: each 1 row x 16 cols
            const int rrow = tid >> 2;          // 0..63
            const int c16 = (tid & 3) * 16;
            float4 v[4];
            #pragma unroll
            for (int q = 0; q < 4; q++) v[q] = make_float4(0.f, 0.f, 0.f, 0.f);
            #pragma unroll
            for (int w = 0; w < 4; w++) {
                const float* fs = (const float*)&lds[w * 8192];
                #pragma unroll
                for (int q = 0; q < 4; q++) {
                    float4 p = *(const float4*)&fs[rrow * 64 + c16 + q * 4];
                    v[q].x += p.x; v[q].y += p.y; v[q].z += p.z; v[q].w += p.w;
                }
            }

            const size_t base = (size_t)(bm2 + rrow) * DIM + bn2 + c16;
            float kv[16], zl[16], zn[16];
            #pragma unroll
            for (int q = 0; q < 4; q++) {
                float4 bb = *(const float4*)&b2[bn2 + c16 + q * 4];
                kv[q * 4 + 0] = v[q].x + bb.x;
                kv[q * 4 + 1] = v[q].y + bb.y;
                kv[q * 4 + 2] = v[q].z + bb.z;
                kv[q * 4 + 3] = v[q].w + bb.w;
                float4 zq = *(const float4*)&z[base + q * 4];
                zl[q * 4 + 0] = zq.x; zl[q * 4 + 1] = zq.y;
                zl[q * 4 + 2] = zq.z; zl[q * 4 + 3] = zq.w;
            }
            if (mode == 0) {
                #pragma unroll
                for (int q = 0; q < 4; q++)
                    *(float4*)&kacc[base + q * 4] =
                        make_float4(kv[q*4], kv[q*4+1], kv[q*4+2], kv[q*4+3]);
                #pragma unroll
                for (int i = 0; i < 16; i++) zn[i] = zl[i] + ah * kv[i];
            } else if (mode == 1) {
                #pragma unroll
                for (int q = 0; q < 4; q++) {
                    float4 ka = *(const float4*)&kacc[base + q * 4];
                    *(float4*)&kacc[base + q * 4] =
                        make_float4(ka.x + wk * kv[q*4],   ka.y + wk * kv[q*4+1],
                                    ka.z + wk * kv[q*4+2], ka.w + wk * kv[q*4+3]);
                }
                #pragma unroll
                for (int i = 0; i < 16; i++) zn[i] = zl[i] + ah * kv[i];
            } else {
                #pragma unroll
                for (int q = 0; q < 4; q++) {
                    float4 ka = *(const float4*)&kacc[base + q * 4];
                    zn[q*4+0] = zl[q*4+0] + h6 * (ka.x + kv[q*4+0]);
                    zn[q*4+1] = zl[q*4+1] + h6 * (ka.y + kv[q*4+1]);
                    zn[q*4+2] = zl[q*4+2] + h6 * (ka.z + kv[q*4+2]);
                    zn[q*4+3] = zl[q*4+3] + h6 * (ka.w + kv[q*4+3]);
                    *(float4*)&z[base + q * 4] =
                        make_float4(zn[q*4], zn[q*4+1], zn[q*4+2], zn[q*4+3]);
                }
            }
            short8 o0, o1;
            #pragma unroll
            for (int i = 0; i < 8; i++) { o0[i] = f2bf(zn[i]); o1[i] = f2bf(zn[8 + i]); }
            *(short8*)&abuf[base] = o0;
            *(short8*)&abuf[base + 8] = o1;
        }
        grid_sync(bar);     // abuf (and z) visible for next eval's phase 1
    }
}

extern "C" void kernel_launch(void* const* d_in, const int* in_sizes, int n_in,
                              void* d_out, int out_size, void* d_ws, size_t ws_size,
                              hipStream_t stream) {
    const float* z0  = (const float*)d_in[0];
    const float* W1  = (const float*)d_in[1];
    const float* b1  = (const float*)d_in[2];
    const float* W2  = (const float*)d_in[3];
    const float* b2  = (const float*)d_in[4];
    const float* t0p = (const float*)d_in[5];
    const float* t1p = (const float*)d_in[6];
    float* z = (float*)d_out;

    char* ws = (char*)d_ws;
    short* W1t    = (short*)(ws);                              // 2 MB
    short* W2t    = (short*)(ws + (2u << 20));                 // 2 MB
    float* w1last = (float*)(ws + (4u << 20));                 // 8 KB
    unsigned* bar = (unsigned*)(ws + (4u << 20) + 32768);      // in the 64 KB pad
    short* abuf   = (short*)(ws + (4u << 20) + (1u << 16));    // 4 MB
    short* hidden = (short*)(ws + (8u << 20) + (1u << 16));    // 16 MB
    float* kacc   = (float*)(ws + (24u << 20) + (1u << 16));   // 8 MB

    (void)hipMemsetAsync(bar, 0, 64, stream);   // barrier ticket = 0 (re-poison safe)
    (void)hipMemcpyAsync(z, z0, (size_t)BATCH * DIM * sizeof(float),
                         hipMemcpyDeviceToDevice, stream);
    transpose_cvt<<<dim3(DIM / 32, HID / 32), dim3(32, 8), 0, stream>>>(W1, W1t, DIM, HID);
    transpose_cvt<<<dim3(HID / 32, DIM / 32), dim3(32, 8), 0, stream>>>(W2, W2t, HID, DIM);
    extract_row<<<HID / 256, 256, 0, stream>>>(W1, w1last);
    init_abuf<<<BATCH * DIM / 4 / 256, 256, 0, stream>>>(z0, abuf);

    rk4_persistent<<<dim3(GRID_NB), dim3(256), 0, stream>>>(
        W1t, W2t, b1, b2, w1last, z, kacc, abuf, hidden, t0p, t1p, bar);
}

// Round 6
// 2982.705 us; speedup vs baseline: 6.7934x; 6.7934x over previous
//
#include <hip/hip_runtime.h>
#include <hip/hip_bf16.h>

#define BATCH 4096
#define DIM   512
#define HID   2048
#define NSTEPS 20

typedef __attribute__((ext_vector_type(8))) short short8;
typedef __attribute__((ext_vector_type(4))) short short4v;
typedef __attribute__((ext_vector_type(4))) float floatx4;

#define GLL(dst, src) __builtin_amdgcn_global_load_lds( \
    (const __attribute__((address_space(1))) void*)(src), \
    (__attribute__((address_space(3))) void*)(dst), 16, 0, 0)

__device__ __forceinline__ short f2bf(float x) {
    union { float f; unsigned u; } v; v.f = x;
    unsigned r = v.u + 0x7fffu + ((v.u >> 16) & 1u);
    return (short)(r >> 16);
}

// tanh(x) = 1 - 2*rcp(1 + exp2(2*log2e*x)); saturates correctly at +-inf
__device__ __forceinline__ float fast_tanh(float x) {
    float e = __builtin_amdgcn_exp2f(x * 2.8853900817779268f);
    float r = __builtin_amdgcn_rcpf(1.0f + e);
    return 1.0f - 2.0f * r;
}

// dst[n][k] = bf16(src[k][n]); src is K x N row-major fp32
__global__ void transpose_cvt(const float* __restrict__ src, short* __restrict__ dst,
                              int K, int N) {
    __shared__ float tile[32][33];
    int k0 = blockIdx.x * 32, n0 = blockIdx.y * 32;
    int tx = threadIdx.x, ty = threadIdx.y;
    #pragma unroll
    for (int r = ty; r < 32; r += 8)
        tile[r][tx] = src[(size_t)(k0 + r) * N + n0 + tx];
    __syncthreads();
    #pragma unroll
    for (int r = ty; r < 32; r += 8)
        dst[(size_t)(n0 + r) * K + k0 + tx] = f2bf(tile[tx][r]);
}

__global__ void extract_row(const float* __restrict__ W1, float* __restrict__ w1last) {
    int i = blockIdx.x * 256 + threadIdx.x;
    w1last[i] = W1[(size_t)DIM * HID + i];
}

__global__ void init_abuf(const float* __restrict__ z0, short* __restrict__ abuf) {
    size_t i = (size_t)(blockIdx.x * 256 + threadIdx.x) * 4;
    float4 zv = *(const float4*)(z0 + i);
    short4v o;
    o[0] = f2bf(zv.x); o[1] = f2bf(zv.y); o[2] = f2bf(zv.z); o[3] = f2bf(zv.w);
    *(short4v*)(abuf + i) = o;
}

// hidden = tanh( A @ W1t^T + b1 + t*w1last ), bf16 out.
// ROUND-0 PROVEN VERSION (verbatim): 128x128 tile, BK=128, XOR-swizzled LDS,
// wave-tile 64x64, 2 blocks/CU, operand-swapped MFMA epilogue.
__global__ __launch_bounds__(256, 2)
void gemm1_tanh(const short* __restrict__ A, const short* __restrict__ Bt,
                const float* __restrict__ b1, const float* __restrict__ w1last,
                const float* __restrict__ t0p, const float* __restrict__ t1p,
                float c_t, float step_i,
                short* __restrict__ hidden) {
    __shared__ short Alds[128 * 128];   // 32 KB
    __shared__ short Blds[128 * 128];   // 32 KB
    const int tid = threadIdx.x;
    const int lane = tid & 63;
    const int wave = tid >> 6;
    const int wm = wave >> 1, wn = wave & 1;
    const int bm0 = blockIdx.x * 128;   // 32 blocks over M
    const int bn0 = blockIdx.y * 128;   // 16 blocks over N

    const float t0 = t0p[0], t1 = t1p[0];
    const float h = (t1 - t0) / (float)NSTEPS;
    const float teval = t0 + (step_i + c_t) * h;

    floatx4 acc[4][4];
    #pragma unroll
    for (int i = 0; i < 4; i++)
        #pragma unroll
        for (int j = 0; j < 4; j++) acc[i][j] = (floatx4)0.f;

    const int fr = lane & 15;
    const int fkc = lane >> 4;     // 0..3
    const int rx = fr & 7;

    for (int kk = 0; kk < DIM; kk += 128) {
        // stage A,B tiles 128x128: 2048 chunks of 16B each, 8/thread
        #pragma unroll
        for (int p = 0; p < 8; p++) {
            int c = tid + p * 256;
            int row = c >> 4;
            int ci = c & 15;
            int g = ((ci & 7) ^ (row & 7)) | (ci & 8);   // swizzle low 3 bits
            GLL(&Alds[c * 8], A  + (size_t)(bm0 + row) * DIM + kk + g * 8);
            GLL(&Blds[c * 8], Bt + (size_t)(bn0 + row) * DIM + kk + g * 8);
        }
        __syncthreads();               // forced vmcnt(0): staging landed
        #pragma unroll
        for (int s = 0; s < 4; s++) {
            const int lc = s * 4 + fkc;                       // logical chunk 0..15
            const int slot = ((((lc & 7) ^ rx) | (lc & 8))) * 8;
            short8 af[4], bfr[4];
            #pragma unroll
            for (int mt = 0; mt < 4; mt++)
                af[mt] = *(const short8*)&Alds[(wm * 64 + mt * 16 + fr) * 128 + slot];
            #pragma unroll
            for (int nt = 0; nt < 4; nt++)
                bfr[nt] = *(const short8*)&Blds[(wn * 64 + nt * 16 + fr) * 128 + slot];
            #pragma unroll
            for (int mt = 0; mt < 4; mt++)
                #pragma unroll
                for (int nt = 0; nt < 4; nt++)   // swapped: lane holds 4 consecutive cols
                    acc[mt][nt] = __builtin_amdgcn_mfma_f32_16x16x32_bf16(bfr[nt], af[mt], acc[mt][nt], 0, 0, 0);
        }
        __syncthreads();
    }
    // epilogue: lane = row m (fr); regs = 4 consecutive cols -> packed 8B stores
    #pragma unroll
    for (int mt = 0; mt < 4; mt++) {
        int m = bm0 + wm * 64 + mt * 16 + fr;
        short* hrow = hidden + (size_t)m * HID;
        #pragma unroll
        for (int nt = 0; nt < 4; nt++) {
            int n0 = bn0 + wn * 64 + nt * 16 + fkc * 4;
            float4 bb = *(const float4*)&b1[n0];
            float4 wl = *(const float4*)&w1last[n0];
            short4v o;
            o[0] = f2bf(fast_tanh(acc[mt][nt][0] + bb.x + teval * wl.x));
            o[1] = f2bf(fast_tanh(acc[mt][nt][1] + bb.y + teval * wl.y));
            o[2] = f2bf(fast_tanh(acc[mt][nt][2] + bb.z + teval * wl.z));
            o[3] = f2bf(fast_tanh(acc[mt][nt][3] + bb.w + teval * wl.w));
            *(short4v*)&hrow[n0] = o;
        }
    }
}

// k = hidden @ W2t^T + b2.  64x64 tile, 256 threads = 4-way K-split across
// waves (wave K=512, 8 iters of BK=64 -- round-0 cadence kept verbatim),
// per-wave private 16 KB slab, 64 KB LDS total -> TRUE 2 blocks/CU, and the
// 512-block grid is resident in ONE dispatch round (round-0's 128 KB version
// ran 1 block/CU in 2 sequential rounds: double tail ramp, no cross-block
// desync). NO barriers in the K-loop (decoupled waves self-stagger). Reduce
// sums 4 partials (half the round-0 reduce traffic).
// mode 0 (k1): kacc = k;            abuf = bf16(z + alpha*h*k)
// mode 1 (k2/k3): kacc += wk*k;     abuf = bf16(z + alpha*h*k)
// mode 2 (k4): z += (h/6)*(kacc+k); abuf = bf16(z_new)
__global__ __launch_bounds__(256, 2)
void gemm2_fused(const short* __restrict__ hidden,  // [BATCH][HID] bf16
                 const short* __restrict__ Bt,      // W2t [DIM][HID] bf16
                 const float* __restrict__ b2,
                 float* __restrict__ z,
                 float* __restrict__ kacc, short* __restrict__ abuf,
                 const float* __restrict__ t0p, const float* __restrict__ t1p,
                 int mode, float wk, float alpha_c) {
    __shared__ short lds[4 * 8192];    // 4 slabs x 16 KB (A[64][64] + B[64][64])
    const int tid = threadIdx.x;
    const int lane = tid & 63;
    const int wave = tid >> 6;          // K-split index 0..3
    const int bm0 = blockIdx.x * 64;    // 64 blocks over M
    const int bn0 = blockIdx.y * 64;    // 8 blocks over N
    const int kbase = wave * 512;

    short* slabA = &lds[wave * 8192];
    short* slabB = slabA + 4096;

    const int fr = lane & 15;
    const int fkc = lane >> 4;     // 0..3
    const int rx = fr & 7;
    const int l3 = lane >> 3;      // 0..7
    const int gch = (lane & 7) ^ l3;   // swizzled global k-chunk for staging

    floatx4 acc[4][4];
    #pragma unroll
    for (int i = 0; i < 4; i++)
        #pragma unroll
        for (int j = 0; j < 4; j++) acc[i][j] = (floatx4)0.f;

    #pragma unroll
    for (int it = 0; it < 8; ++it) {
        const int k0 = kbase + it * 64;
        // drain own ds_reads before overwriting slab (lgkmcnt(0), vmcnt don't-care)
        __builtin_amdgcn_s_waitcnt(0xC07F);
        #pragma unroll
        for (int j = 0; j < 8; j++) {
            int row = j * 8 + l3;
            GLL(&slabA[j * 512 + lane * 8], hidden + (size_t)(bm0 + row) * HID + k0 + gch * 8);
            GLL(&slabB[j * 512 + lane * 8], Bt     + (size_t)(bn0 + row) * HID + k0 + gch * 8);
        }
        __builtin_amdgcn_sched_barrier(0);
        __builtin_amdgcn_s_waitcnt(0x0F70);   // vmcnt(0) only, per-wave
        __builtin_amdgcn_sched_barrier(0);
        #pragma unroll
        for (int s = 0; s < 2; s++) {
            const int slot = ((s * 4 + fkc) ^ rx) * 8;
            short8 af[4], bfr[4];
            #pragma unroll
            for (int mt = 0; mt < 4; mt++)
                af[mt] = *(const short8*)&slabA[(mt * 16 + fr) * 64 + slot];
            #pragma unroll
            for (int nt = 0; nt < 4; nt++)
                bfr[nt] = *(const short8*)&slabB[(nt * 16 + fr) * 64 + slot];
            #pragma unroll
            for (int mt = 0; mt < 4; mt++)
                #pragma unroll
                for (int nt = 0; nt < 4; nt++)
                    acc[mt][nt] = __builtin_amdgcn_mfma_f32_16x16x32_bf16(af[mt], bfr[nt], acc[mt][nt], 0, 0, 0);
        }
        __builtin_amdgcn_sched_barrier(0);
    }

    // write partial acc (fp32 [64][64]) into own slab, then reduce across 4 waves
    __builtin_amdgcn_s_waitcnt(0xC07F);   // lgkmcnt(0): own ds_reads done
    float* fslab = (float*)slabA;
    #pragma unroll
    for (int mt = 0; mt < 4; mt++)
        #pragma unroll
        for (int nt = 0; nt < 4; nt++)
            #pragma unroll
            for (int r = 0; r < 4; r++) {
                int row = mt * 16 + fkc * 4 + r;
                int col = nt * 16 + fr;
                fslab[row * 64 + col] = acc[mt][nt][r];
            }
    __syncthreads();

    // 256 threads: each handles 1 row x 16 cols; sum 4 K-partials
    const int rrow = tid >> 2;          // 0..63
    const int c16 = (tid & 3) * 16;     // col chunk of 16
    float4 v[4];
    #pragma unroll
    for (int q = 0; q < 4; q++) v[q] = make_float4(0.f, 0.f, 0.f, 0.f);
    #pragma unroll
    for (int w = 0; w < 4; w++) {
        const float* fs = (const float*)&lds[w * 8192];
        #pragma unroll
        for (int q = 0; q < 4; q++) {
            float4 p = *(const float4*)&fs[rrow * 64 + c16 + q * 4];
            v[q].x += p.x; v[q].y += p.y; v[q].z += p.z; v[q].w += p.w;
        }
    }

    const float h = (t1p[0] - t0p[0]) / (float)NSTEPS;
    const float ah = alpha_c * h;
    const float h6 = h / 6.0f;
    const size_t base = (size_t)(bm0 + rrow) * DIM + bn0 + c16;

    float kv[16], zl[16], zn[16];
    #pragma unroll
    for (int q = 0; q < 4; q++) {
        float4 bb = *(const float4*)&b2[bn0 + c16 + q * 4];
        kv[q * 4 + 0] = v[q].x + bb.x;
        kv[q * 4 + 1] = v[q].y + bb.y;
        kv[q * 4 + 2] = v[q].z + bb.z;
        kv[q * 4 + 3] = v[q].w + bb.w;
        float4 zq = *(const float4*)&z[base + q * 4];
        zl[q * 4 + 0] = zq.x; zl[q * 4 + 1] = zq.y;
        zl[q * 4 + 2] = zq.z; zl[q * 4 + 3] = zq.w;
    }
    if (mode == 0) {
        #pragma unroll
        for (int q = 0; q < 4; q++)
            *(float4*)&kacc[base + q * 4] =
                make_float4(kv[q*4], kv[q*4+1], kv[q*4+2], kv[q*4+3]);
        #pragma unroll
        for (int i = 0; i < 16; i++) zn[i] = zl[i] + ah * kv[i];
    } else if (mode == 1) {
        #pragma unroll
        for (int q = 0; q < 4; q++) {
            float4 ka = *(const float4*)&kacc[base + q * 4];
            *(float4*)&kacc[base + q * 4] =
                make_float4(ka.x + wk * kv[q*4],   ka.y + wk * kv[q*4+1],
                            ka.z + wk * kv[q*4+2], ka.w + wk * kv[q*4+3]);
        }
        #pragma unroll
        for (int i = 0; i < 16; i++) zn[i] = zl[i] + ah * kv[i];
    } else {
        #pragma unroll
        for (int q = 0; q < 4; q++) {
            float4 ka = *(const float4*)&kacc[base + q * 4];
            zn[q*4+0] = zl[q*4+0] + h6 * (ka.x + kv[q*4+0]);
            zn[q*4+1] = zl[q*4+1] + h6 * (ka.y + kv[q*4+1]);
            zn[q*4+2] = zl[q*4+2] + h6 * (ka.z + kv[q*4+2]);
            zn[q*4+3] = zl[q*4+3] + h6 * (ka.w + kv[q*4+3]);
            *(float4*)&z[base + q * 4] =
                make_float4(zn[q*4], zn[q*4+1], zn[q*4+2], zn[q*4+3]);
        }
    }
    short8 o0, o1;
    #pragma unroll
    for (int i = 0; i < 8; i++) { o0[i] = f2bf(zn[i]); o1[i] = f2bf(zn[8 + i]); }
    *(short8*)&abuf[base] = o0;
    *(short8*)&abuf[base + 8] = o1;
}

extern "C" void kernel_launch(void* const* d_in, const int* in_sizes, int n_in,
                              void* d_out, int out_size, void* d_ws, size_t ws_size,
                              hipStream_t stream) {
    const float* z0  = (const float*)d_in[0];
    const float* W1  = (const float*)d_in[1];
    const float* b1  = (const float*)d_in[2];
    const float* W2  = (const float*)d_in[3];
    const float* b2  = (const float*)d_in[4];
    const float* t0p = (const float*)d_in[5];
    const float* t1p = (const float*)d_in[6];
    float* z = (float*)d_out;

    char* ws = (char*)d_ws;
    short* W1t    = (short*)(ws);                              // 2 MB
    short* W2t    = (short*)(ws + (2u << 20));                 // 2 MB
    float* w1last = (float*)(ws + (4u << 20));                 // 8 KB (pad 64 KB)
    short* abuf   = (short*)(ws + (4u << 20) + (1u << 16));    // 4 MB
    short* hidden = (short*)(ws + (8u << 20) + (1u << 16));    // 16 MB
    float* kacc   = (float*)(ws + (24u << 20) + (1u << 16));   // 8 MB

    (void)hipMemcpyAsync(z, z0, (size_t)BATCH * DIM * sizeof(float),
                         hipMemcpyDeviceToDevice, stream);
    transpose_cvt<<<dim3(DIM / 32, HID / 32), dim3(32, 8), 0, stream>>>(W1, W1t, DIM, HID);
    transpose_cvt<<<dim3(HID / 32, DIM / 32), dim3(32, 8), 0, stream>>>(W2, W2t, HID, DIM);
    extract_row<<<HID / 256, 256, 0, stream>>>(W1, w1last);
    init_abuf<<<BATCH * DIM / 4 / 256, 256, 0, stream>>>(z0, abuf);

    const dim3 g1(BATCH / 128, HID / 128), g2(BATCH / 64, DIM / 64);
    const dim3 b1d(256), b2d(256);
    for (int i = 0; i < NSTEPS; i++) {
        float fi = (float)i;
        // k1 -> abuf for k2
        gemm1_tanh<<<g1, b1d, 0, stream>>>(abuf, W1t, b1, w1last, t0p, t1p, 0.0f, fi, hidden);
        gemm2_fused<<<g2, b2d, 0, stream>>>(hidden, W2t, b2, z, kacc, abuf, t0p, t1p, 0, 1.0f, 0.5f);
        // k2 -> abuf for k3
        gemm1_tanh<<<g1, b1d, 0, stream>>>(abuf, W1t, b1, w1last, t0p, t1p, 0.5f, fi, hidden);
        gemm2_fused<<<g2, b2d, 0, stream>>>(hidden, W2t, b2, z, kacc, abuf, t0p, t1p, 1, 2.0f, 0.5f);
        // k3 -> abuf for k4
        gemm1_tanh<<<g1, b1d, 0, stream>>>(abuf, W1t, b1, w1last, t0p, t1p, 0.5f, fi, hidden);
        gemm2_fused<<<g2, b2d, 0, stream>>>(hidden, W2t, b2, z, kacc, abuf, t0p, t1p, 1, 2.0f, 1.0f);
        // k4: z += (h/6)*(kacc + k4) ; abuf = bf16(z_new)
        gemm1_tanh<<<g1, b1d, 0, stream>>>(abuf, W1t, b1, w1last, t0p, t1p, 1.0f, fi, hidden);
        gemm2_fused<<<g2, b2d, 0, stream>>>(hidden, W2t, b2, z, kacc, abuf, t0p, t1p, 2, 1.0f, 0.0f);
    }
}